// Round 1
// baseline (574.256 us; speedup 1.0000x reference)
//
#include <hip/hip_runtime.h>

constexpr int CH  = 64;    // input channels
constexpr int HW  = 11;    // spatial
constexpr int PH  = 13;    // padded height
constexpr int PW  = 14;    // padded row stride (floats) - 11 distinct banks across rows
constexpr int OCT = 20;    // output channels per iteration (100 = 5 * 20)
constexpr int WSTRIDE = 584; // per-oc stride in wbuf (584%32==8 -> 2-way max)
constexpr float EPS = 1e-5f;

__launch_bounds__(256, 1)
__global__ void fused_hsi_kernel(const float* __restrict__ x_in,
                                 const float* __restrict__ gw,   // [6400,2,3,3]
                                 const float* __restrict__ gb,   // [6400]
                                 const float* __restrict__ bng,  // gamma
                                 const float* __restrict__ bnb,  // beta
                                 const float* __restrict__ bnm,  // mean
                                 const float* __restrict__ bnv,  // var
                                 float* __restrict__ out)        // [B,100,11,11]
{
    __shared__ float xs[CH * PH * PW];     // 46592 B padded input
    __shared__ float xH[2 * 128];          // 1024 B pooled (avg | max)
    __shared__ float wbuf[OCT * WSTRIDE];  // 46720 B generated weights

    const int b = blockIdx.x;
    const int t = threadIdx.x;
    const float* xb = x_in + (size_t)b * (CH * HW * HW);

    // ---- Phase A: zero-fill padded LDS, then load sample ----
    for (int i = t; i < CH * PH * PW; i += 256) xs[i] = 0.f;
    __syncthreads();
    for (int i = t; i < CH * HW * HW; i += 256) {
        int ic = i / (HW * HW);
        int p  = i - ic * (HW * HW);
        int r = p / HW, c = p - r * HW;
        xs[(ic * PH + (r + 1)) * PW + (c + 1)] = xb[i];
    }
    __syncthreads();

    // ---- Phase B: channel pool (mean, max) -> xH[2][121] ----
    if (t < HW * HW) {
        int r = t / HW, c = t - r * HW;
        float s = 0.f, m = -INFINITY;
        for (int ic = 0; ic < CH; ++ic) {
            float v = xs[(ic * PH + (r + 1)) * PW + (c + 1)];
            s += v;
            m = fmaxf(m, v);
        }
        xH[t]       = s * (1.f / CH);
        xH[128 + t] = m;
    }
    __syncthreads();

    const int ocl = t / HW;        // 0..19 for t<220
    const int r   = t - ocl * HW;  // output row

    for (int oc0 = 0; oc0 < 100; oc0 += OCT) {
        // ---- Phase C1: generate weights for ocs [oc0, oc0+OCT) ----
        // w[oc][ic][kh][kw] = relu(BN(genconv(o=oc*64+ic, i=kh, j=kw)))
        for (int e = t; e < OCT * CH * 9; e += 256) {   // 11520 = 45*256 exactly
            int ocw = e / (CH * 9);
            int rem = e - ocw * (CH * 9);
            int ic  = rem / 9;
            int k   = rem - ic * 9;
            int kh = k / 3, kw = k - kh * 3;
            int o  = (oc0 + ocw) * CH + ic;
            const float* gwo = gw + o * 18;
            float acc = 0.f;
            #pragma unroll
            for (int ci = 0; ci < 2; ++ci)
                #pragma unroll
                for (int u = 0; u < 3; ++u)
                    #pragma unroll
                    for (int v = 0; v < 3; ++v)
                        acc = fmaf(xH[ci * 128 + (4*kh + u) * HW + (4*kw + v)],
                                   gwo[ci * 9 + u * 3 + v], acc);
            float inv = bng[o] * rsqrtf(bnv[o] + EPS);
            float val = (acc + gb[o] - bnm[o]) * inv + bnb[o];
            wbuf[ocw * WSTRIDE + rem] = fmaxf(val, 0.f);
        }
        __syncthreads();

        // ---- Phase C2: per-sample conv, thread = (oc, output row) ----
        if (t < OCT * HW) {
            float acc[HW];
            #pragma unroll
            for (int c = 0; c < HW; ++c) acc[c] = 0.f;

            for (int ic = 0; ic < CH; ++ic) {
                // 3 padded rows into registers (float2 aligned, conflict-free)
                float xr[3][PW];
                #pragma unroll
                for (int kh = 0; kh < 3; ++kh) {
                    const float* rp = &xs[(ic * PH + (r + kh)) * PW];
                    #pragma unroll
                    for (int cc = 0; cc < PW; cc += 2) {
                        float2 v = *reinterpret_cast<const float2*>(rp + cc);
                        xr[kh][cc] = v.x; xr[kh][cc + 1] = v.y;
                    }
                }
                const float* wp = &wbuf[ocl * WSTRIDE + ic * 9];
                float w[9];
                #pragma unroll
                for (int k = 0; k < 9; ++k) w[k] = wp[k];

                #pragma unroll
                for (int kh = 0; kh < 3; ++kh)
                    #pragma unroll
                    for (int kw = 0; kw < 3; ++kw)
                        #pragma unroll
                        for (int c = 0; c < HW; ++c)
                            acc[c] = fmaf(xr[kh][c + kw], w[kh * 3 + kw], acc[c]);
            }
            float* op = out + ((size_t)b * 100 + (oc0 + ocl)) * (HW * HW) + r * HW;
            #pragma unroll
            for (int c = 0; c < HW; ++c) op[c] = acc[c];
        }
        __syncthreads();
    }
}

extern "C" void kernel_launch(void* const* d_in, const int* in_sizes, int n_in,
                              void* d_out, int out_size, void* d_ws, size_t ws_size,
                              hipStream_t stream) {
    const float* x  = (const float*)d_in[0];
    const float* gw = (const float*)d_in[1];
    const float* gb = (const float*)d_in[2];
    const float* bg = (const float*)d_in[3];
    const float* bb = (const float*)d_in[4];
    const float* bm = (const float*)d_in[5];
    const float* bv = (const float*)d_in[6];
    float* out = (float*)d_out;

    const int nb = in_sizes[0] / (CH * HW * HW);  // batch = 1024
    fused_hsi_kernel<<<nb, 256, 0, stream>>>(x, gw, gb, bg, bb, bm, bv, out);
}

// Round 2
// 95.426 us; speedup vs baseline: 6.0178x; 6.0178x over previous
//
#include <hip/hip_runtime.h>
#include <hip/hip_bf16.h>

using bf16x8 = __attribute__((ext_vector_type(8))) short;
using f32x4  = __attribute__((ext_vector_type(4))) float;

constexpr int CH  = 64;    // input channels
constexpr int HW  = 11;    // spatial
constexpr int NP  = 121;   // positions
constexpr int PPW = 14;    // padded pos row width (13x14 grid)
constexpr int NPP = 182;   // padded positions
constexpr int ICP = 72;    // padded ic stride (bf16) -> 144B rows, 2-way banks
constexpr int OCT = 32;    // oc chunk (2 M-tiles)
constexpr float EPS = 1e-5f;

__launch_bounds__(256, 2)
__global__ void hsi_fused(const float* __restrict__ x_in,
                          const float* __restrict__ gw,   // [6400,2,3,3]
                          const float* __restrict__ gb,
                          const float* __restrict__ bng,
                          const float* __restrict__ bnb,
                          const float* __restrict__ bnm,
                          const float* __restrict__ bnv,
                          float* __restrict__ out)        // [B,100,11,11]
{
    __shared__ alignas(16) unsigned short xsT[NPP][ICP];   // 26208 B  x[pos_pad][ic] bf16
    __shared__ alignas(16) unsigned short Wc[9][OCT][ICP]; // 41472 B  W[tap][ocloc][ic] bf16
    __shared__ float xh[2][128];                           // pooled avg|max
    __shared__ alignas(16) float xtap[9][20];              // per-tap 18 gen-conv inputs

    const int b = blockIdx.x;
    const int t = threadIdx.x;
    const float* xb = x_in + (size_t)b * (CH * NP);

    // ---- zero padded xsT ----
    for (int i = t; i < NPP * ICP / 2; i += 256) ((unsigned int*)xsT)[i] = 0u;
    __syncthreads();

    // ---- pooling (fp32) + bf16 transpose-staging ----
    if (t < NP) {
        int r = t / HW, c = t - r * HW;
        int pp = (r + 1) * PPW + (c + 1);
        float s = 0.f, m = -INFINITY;
        for (int ic = 0; ic < CH; ++ic) {
            float v = xb[ic * NP + t];           // coalesced across lanes
            s += v; m = fmaxf(m, v);
            __hip_bfloat16 h = __float2bfloat16(v);
            xsT[pp][ic] = *(const unsigned short*)&h;
        }
        xh[0][t] = s * (1.f / 64.f);
        xh[1][t] = m;
    }
    __syncthreads();

    // ---- per-tap gen-conv input vectors (18 each) ----
    if (t < 162) {
        int tap = t / 18, k = t - tap * 18;
        int ci = k / 9, o9 = k - ci * 9;
        int u = o9 / 3, v = o9 - u * 3;
        int kh = tap / 3, kw = tap - kh * 3;
        xtap[tap][k] = xh[ci][(4 * kh + u) * HW + (4 * kw + v)];
    }
    __syncthreads();

    const int lane = t & 63, wave = t >> 6;
    const int lrow = lane & 15, jg = lane >> 4;

    // B-fragment positional bases for this wave's two N-tiles
    int ppb[2], pst[2];
    #pragma unroll
    for (int nt = 0; nt < 2; ++nt) {
        int p = wave * 32 + nt * 16 + lrow;
        pst[nt] = p;
        int pc = p > 120 ? 120 : p;
        int r = pc / HW, c = pc - r * HW;
        ppb[nt] = r * PPW + c;
    }

    for (int oc0 = 0; oc0 < 100; oc0 += OCT) {
        // last chunk: zero pad rows 4..31 (ocs >= 100)
        if (oc0 == 96) {
            for (int i = t; i < 9 * 28 * ICP / 2; i += 256) {
                int tap = i / 1008, rem = i - tap * 1008;
                ((unsigned int*)&Wc[tap][4][0])[rem] = 0u;
            }
        }

        // ---- gen phase: fp32 filter generation + BN + ReLU -> bf16 LDS ----
        const int nGen = (oc0 == 96 ? 4 : OCT) * CH;
        for (int i = t; i < nGen; i += 256) {
            int o = oc0 * CH + i;
            int ocl = i >> 6, ic = i & 63;
            const float2* gp = (const float2*)(gw + (size_t)o * 18);
            float wv[18];
            #pragma unroll
            for (int q = 0; q < 9; ++q) { float2 g = gp[q]; wv[2*q] = g.x; wv[2*q+1] = g.y; }
            float inv  = bng[o] * rsqrtf(bnv[o] + EPS);
            float beta = (gb[o] - bnm[o]) * inv + bnb[o];
            #pragma unroll
            for (int tap = 0; tap < 9; ++tap) {
                float4 a0 = *(const float4*)&xtap[tap][0];
                float4 a1 = *(const float4*)&xtap[tap][4];
                float4 a2 = *(const float4*)&xtap[tap][8];
                float4 a3 = *(const float4*)&xtap[tap][12];
                float2 a4 = *(const float2*)&xtap[tap][16];
                float xt[18] = {a0.x,a0.y,a0.z,a0.w, a1.x,a1.y,a1.z,a1.w,
                                a2.x,a2.y,a2.z,a2.w, a3.x,a3.y,a3.z,a3.w, a4.x,a4.y};
                float s0 = 0.f, s1 = 0.f;
                #pragma unroll
                for (int q = 0; q < 9; ++q) {
                    s0 = fmaf(wv[2*q],   xt[2*q],   s0);
                    s1 = fmaf(wv[2*q+1], xt[2*q+1], s1);
                }
                float val = fmaxf(fmaf(s0 + s1, inv, beta), 0.f);
                __hip_bfloat16 h = __float2bfloat16(val);
                Wc[tap][ocl][ic] = *(const unsigned short*)&h;
            }
        }
        __syncthreads();

        // ---- MFMA phase: 2 M-tiles x 2 N-tiles per wave ----
        f32x4 acc00{}, acc01{}, acc10{}, acc11{};
        #pragma unroll
        for (int tap = 0; tap < 9; ++tap) {
            const int tapoff = (tap / 3) * PPW + (tap % 3);
            #pragma unroll
            for (int k0 = 0; k0 < 64; k0 += 32) {
                const int kk = k0 + jg * 8;
                bf16x8 A0 = *(const bf16x8*)&Wc[tap][lrow][kk];
                bf16x8 A1 = *(const bf16x8*)&Wc[tap][16 + lrow][kk];
                bf16x8 B0 = *(const bf16x8*)&xsT[ppb[0] + tapoff][kk];
                bf16x8 B1 = *(const bf16x8*)&xsT[ppb[1] + tapoff][kk];
                acc00 = __builtin_amdgcn_mfma_f32_16x16x32_bf16(A0, B0, acc00, 0, 0, 0);
                acc01 = __builtin_amdgcn_mfma_f32_16x16x32_bf16(A0, B1, acc01, 0, 0, 0);
                acc10 = __builtin_amdgcn_mfma_f32_16x16x32_bf16(A1, B0, acc10, 0, 0, 0);
                acc11 = __builtin_amdgcn_mfma_f32_16x16x32_bf16(A1, B1, acc11, 0, 0, 0);
            }
        }

        // ---- store: C/D layout col=lane&15, row=(lane>>4)*4+reg (m89) ----
        #pragma unroll
        for (int mt = 0; mt < 2; ++mt) {
            #pragma unroll
            for (int nt = 0; nt < 2; ++nt) {
                f32x4 vv = (mt == 0) ? (nt == 0 ? acc00 : acc01)
                                     : (nt == 0 ? acc10 : acc11);
                int p = pst[nt];
                if (p < NP) {
                    #pragma unroll
                    for (int ri = 0; ri < 4; ++ri) {
                        int oc = oc0 + mt * 16 + jg * 4 + ri;
                        if (oc < 100)
                            out[((size_t)b * 100 + oc) * NP + p] = vv[ri];
                    }
                }
            }
        }
        __syncthreads();   // Wc reuse + acc done before next gen
    }
}

extern "C" void kernel_launch(void* const* d_in, const int* in_sizes, int n_in,
                              void* d_out, int out_size, void* d_ws, size_t ws_size,
                              hipStream_t stream) {
    const float* x  = (const float*)d_in[0];
    const float* gw = (const float*)d_in[1];
    const float* gb = (const float*)d_in[2];
    const float* bg = (const float*)d_in[3];
    const float* bb = (const float*)d_in[4];
    const float* bm = (const float*)d_in[5];
    const float* bv = (const float*)d_in[6];
    float* out = (float*)d_out;

    const int nb = in_sizes[0] / (CH * NP);  // 1024
    hsi_fused<<<nb, 256, 0, stream>>>(x, gw, gb, bg, bb, bm, bv, out);
}